// Round 2
// baseline (533.065 us; speedup 1.0000x reference)
//
#include <hip/hip_runtime.h>

typedef __attribute__((ext_vector_type(4))) float f32x4;
typedef __attribute__((ext_vector_type(16))) float f32x16;
typedef __attribute__((ext_vector_type(4))) unsigned short u16x4;
typedef __attribute__((ext_vector_type(4))) int i32x4;
typedef __attribute__((ext_vector_type(8))) __bf16 bf16x8;

union FragAB {
  u16x4 u[2];
  i32x4 v;
  bf16x8 f;
};

static __device__ __forceinline__ unsigned short f2bf(float x) {
  union { float f; unsigned u; } v;
  v.f = x;
  unsigned r = v.u + 0x7FFFu + ((v.u >> 16) & 1u);  // round-to-nearest-even
  return (unsigned short)(r >> 16);
}

#define NN 8192

// ---------- kernel 1: prep = bias broadcast + adj int32 -> 2-bit pack ----------
// adj2 dword g packs adj elems [16g, 16g+16), elem i at bits 2i (row-major,
// 512 dwords per row). One dedicated streaming pass moves the 256 MB at full
// HBM BW instead of letting k_agg's barrier-drained prefetch trickle it at 1 TB/s.
__global__ __launch_bounds__(256) void k_prep(const int* __restrict__ adj,
                                              const float* __restrict__ bias,
                                              unsigned* __restrict__ adj2,
                                              float* __restrict__ out) {
  int t = blockIdx.x * 256 + threadIdx.x;
  int nT = gridDim.x * 256;
  for (int g = t; g < 4194304; g += nT) {   // 16M elems / 16 per dword
    const int* p = adj + (size_t)g * 16;
    i32x4 a0 = *(const i32x4*)(p);
    i32x4 a1 = *(const i32x4*)(p + 4);
    i32x4 a2 = *(const i32x4*)(p + 8);
    i32x4 a3 = *(const i32x4*)(p + 12);
    unsigned w = (unsigned)(a0.x & 3)        | ((unsigned)(a0.y & 3) << 2)  |
                 ((unsigned)(a0.z & 3) << 4) | ((unsigned)(a0.w & 3) << 6)  |
                 ((unsigned)(a1.x & 3) << 8) | ((unsigned)(a1.y & 3) << 10) |
                 ((unsigned)(a1.z & 3) << 12)| ((unsigned)(a1.w & 3) << 14) |
                 ((unsigned)(a2.x & 3) << 16)| ((unsigned)(a2.y & 3) << 18) |
                 ((unsigned)(a2.z & 3) << 20)| ((unsigned)(a2.w & 3) << 22) |
                 ((unsigned)(a3.x & 3) << 24)| ((unsigned)(a3.y & 3) << 26) |
                 ((unsigned)(a3.z & 3) << 28)| ((unsigned)(a3.w & 3) << 30);
    adj2[g] = w;
  }
  for (int g = t; g < 524288; g += nT) {    // out = bias broadcast, f32x4
    *(f32x4*)(out + (size_t)g * 4) = *(const f32x4*)(bias + ((g * 4) & 255));
  }
}

// ---------- kernel 2: Bp = (V @ Wcat)^T in k-blocked layout, bf16 (unchanged) ----------
// Bp element (ty, n, j) at  ty*2097152 + (j>>4)*4096 + n*16 + (j&15).
__global__ __launch_bounds__(256) void k_transform(
    const float* __restrict__ V, const float* __restrict__ w1,
    const float* __restrict__ w2, const float* __restrict__ w3,
    unsigned short* __restrict__ Bp) {
  int bx = blockIdx.x;
  int rb = bx & 63;   // j tile of 128
  int nb = bx >> 6;   // 0..11 (64-wide col tile within 768)
  const float* W = (nb < 4) ? w1 : (nb < 8) ? w2 : w3;
  int nc0 = (nb & 3) * 64;
  int tid = threadIdx.x;
  int lane = tid & 63;
  int wv = tid >> 6;
  int wm = wv >> 1, wn = wv & 1;
  int q = lane >> 4, l16 = lane & 15;

  __shared__ unsigned short tA[128][36];  // V tile bf16, padded (72B rows)
  __shared__ unsigned short tB[64][36];   // W tile transposed [n][c]

  f32x4 acc[4][2];
#pragma unroll
  for (int i = 0; i < 4; i++)
#pragma unroll
    for (int j = 0; j < 2; j++) acc[i][j] = (f32x4)0.0f;

  for (int kk = 0; kk < 256; kk += 32) {
    {
      int r = tid >> 1, c0 = (tid & 1) * 16;
      const float* src = V + (size_t)(rb * 128 + r) * 256 + kk + c0;
      f32x4 f0 = *(const f32x4*)(src + 0);
      f32x4 f1 = *(const f32x4*)(src + 4);
      f32x4 f2 = *(const f32x4*)(src + 8);
      f32x4 f3 = *(const f32x4*)(src + 12);
      unsigned short* d = &tA[r][c0];
      d[0] = f2bf(f0.x);  d[1] = f2bf(f0.y);  d[2] = f2bf(f0.z);  d[3] = f2bf(f0.w);
      d[4] = f2bf(f1.x);  d[5] = f2bf(f1.y);  d[6] = f2bf(f1.z);  d[7] = f2bf(f1.w);
      d[8] = f2bf(f2.x);  d[9] = f2bf(f2.y);  d[10] = f2bf(f2.z); d[11] = f2bf(f2.w);
      d[12] = f2bf(f3.x); d[13] = f2bf(f3.y); d[14] = f2bf(f3.z); d[15] = f2bf(f3.w);
    }
    {
      int r = tid >> 3, c0 = (tid & 7) * 8;
      const float* src = W + (size_t)(kk + r) * 256 + nc0 + c0;
      f32x4 g0 = *(const f32x4*)(src);
      f32x4 g1 = *(const f32x4*)(src + 4);
      tB[c0 + 0][r] = f2bf(g0.x); tB[c0 + 1][r] = f2bf(g0.y);
      tB[c0 + 2][r] = f2bf(g0.z); tB[c0 + 3][r] = f2bf(g0.w);
      tB[c0 + 4][r] = f2bf(g1.x); tB[c0 + 5][r] = f2bf(g1.y);
      tB[c0 + 6][r] = f2bf(g1.z); tB[c0 + 7][r] = f2bf(g1.w);
    }
    __syncthreads();
    FragAB af[4], bf[2];
#pragma unroll
    for (int mt = 0; mt < 4; mt++) {
      const unsigned short* p = &tA[wm * 64 + mt * 16 + l16][q * 8];
      af[mt].u[0] = *(const u16x4*)p;
      af[mt].u[1] = *(const u16x4*)(p + 4);
    }
#pragma unroll
    for (int nt = 0; nt < 2; nt++) {
      const unsigned short* p = &tB[wn * 32 + nt * 16 + l16][q * 8];
      bf[nt].u[0] = *(const u16x4*)p;
      bf[nt].u[1] = *(const u16x4*)(p + 4);
    }
#pragma unroll
    for (int mt = 0; mt < 4; mt++)
#pragma unroll
      for (int nt = 0; nt < 2; nt++)
        acc[mt][nt] = __builtin_amdgcn_mfma_f32_16x16x32_bf16(
            af[mt].f, bf[nt].f, acc[mt][nt], 0, 0, 0);
    __syncthreads();
  }
  int ty = nb >> 2;
#pragma unroll
  for (int mt = 0; mt < 4; mt++)
#pragma unroll
    for (int nt = 0; nt < 2; nt++) {
      int n = (nb & 3) * 64 + wn * 32 + nt * 16 + l16;
      int j0 = rb * 128 + wm * 64 + mt * 16 + q * 4;
      u16x4 hv;
      hv.x = f2bf(acc[mt][nt].x);
      hv.y = f2bf(acc[mt][nt].y);
      hv.z = f2bf(acc[mt][nt].z);
      hv.w = f2bf(acc[mt][nt].w);
      size_t idx = (size_t)ty * 2097152 + (size_t)(j0 >> 4) * 4096 + n * 16 + (j0 & 15);
      *(u16x4*)(Bp + idx) = hv;
    }
}

// ---------- kernel 3: out += sum_k (adj==k) @ H_k ----------
// v4: barrier-free, LDS-free. BM=128, BN=128, BK=32, splitK=8 -> grid
// 64rb x 2nb x 8ks = 1024 blocks (4/CU, 16 waves/CU at <=128 VGPR).
// 4 waves (2 wm x 2 wn), each owns a 64x64 output tile (acc = 4x f32x16).
// A-fragments are built IN REGISTERS from 2-bit adj codes using the
// mfma_32x32x16 A-layout (row = lane&31, k = q*8+e): lane loads 8 B of adj2
// per row per step (dwordx2), shifts out its 16-bit window, compares to ty.
// No __syncthreads -> no vmcnt(0) drains -> adj2/B loads stay pipelined.
// ks = bx&7 -> per-XCD L2 holds both its Bp slice (1.5 MB) and adj2 slice (2 MB).
__global__ __launch_bounds__(256, 4) void k_agg(const unsigned* __restrict__ adj2,
                                                const unsigned short* __restrict__ Bp,
                                                float* __restrict__ out) {
  int bx = blockIdx.x;
  int ks = bx & 7, rb = (bx >> 3) & 63, nb = bx >> 9;
  int tid = threadIdx.x, lane = tid & 63;
  int wv = tid >> 6;
  int wm = wv >> 1, wn = wv & 1;
  int q = lane >> 5, l32 = lane & 31;
  int qsh = q << 4;

  f32x16 acc[2][2];
  acc[0][0] = (f32x16)0.0f;
  acc[0][1] = (f32x16)0.0f;
  acc[1][0] = (f32x16)0.0f;
  acc[1][1] = (f32x16)0.0f;

  // adj2: 512 dwords per row; this lane's two rows (mt=0,1), ks k-slice.
  const unsigned* ap0 = adj2 + (size_t)(rb * 128 + wm * 64 + l32) * 512 + ks * 64;
  const unsigned* ap1 = ap0 + 32 * 512;

  // B base: elem = ty*2097152 + ks*262144 + n*16 + q*8  (+ step*8192 + kh*4096 + nt*512)
  int n0 = nb * 128 + wn * 64 + l32;
  const unsigned short* bp = Bp + (size_t)ks * 262144 + (size_t)n0 * 16 + q * 8;

  unsigned long long c0 = *(const unsigned long long*)ap0;  // 32 elems row mt=0
  unsigned long long c1 = *(const unsigned long long*)ap1;  // 32 elems row mt=1

  for (int step = 0; step < 32; ++step) {
    unsigned long long nx0 = 0, nx1 = 0;
    if (step < 31) {  // register prefetch, 1 step ahead of use
      nx0 = *(const unsigned long long*)(ap0 + 2 * (step + 1));
      nx1 = *(const unsigned long long*)(ap1 + 2 * (step + 1));
    }
#pragma unroll
    for (int kh = 0; kh < 2; kh++) {
      FragAB bv[3][2];
#pragma unroll
      for (int ty = 0; ty < 3; ty++)
#pragma unroll
        for (int nt = 0; nt < 2; nt++)
          bv[ty][nt].v =
              *(const i32x4*)(bp + (size_t)ty * 2097152 + kh * 4096 + nt * 512);
      // this lane's 8-elem window: elems kh*16 + q*8 + e, 2 bits each
      unsigned w0 = (unsigned)(kh ? (c0 >> 32) : c0) >> qsh;
      unsigned w1 = (unsigned)(kh ? (c1 >> 32) : c1) >> qsh;
#pragma unroll
      for (int ty = 0; ty < 3; ty++) {
        FragAB A0, A1;
#pragma unroll
        for (int d = 0; d < 4; d++) {  // dword d packs bf16 elems 2d, 2d+1
          unsigned p00 = (w0 >> (4 * d)) & 3u, p01 = (w0 >> (4 * d + 2)) & 3u;
          unsigned p10 = (w1 >> (4 * d)) & 3u, p11 = (w1 >> (4 * d + 2)) & 3u;
          A0.v[d] = (int)((p00 == (unsigned)(ty + 1) ? 0x3F80u : 0u) |
                          (p01 == (unsigned)(ty + 1) ? 0x3F800000u : 0u));
          A1.v[d] = (int)((p10 == (unsigned)(ty + 1) ? 0x3F80u : 0u) |
                          (p11 == (unsigned)(ty + 1) ? 0x3F800000u : 0u));
        }
        acc[0][0] = __builtin_amdgcn_mfma_f32_32x32x16_bf16(A0.f, bv[ty][0].f,
                                                            acc[0][0], 0, 0, 0);
        acc[0][1] = __builtin_amdgcn_mfma_f32_32x32x16_bf16(A0.f, bv[ty][1].f,
                                                            acc[0][1], 0, 0, 0);
        acc[1][0] = __builtin_amdgcn_mfma_f32_32x32x16_bf16(A1.f, bv[ty][0].f,
                                                            acc[1][0], 0, 0, 0);
        acc[1][1] = __builtin_amdgcn_mfma_f32_32x32x16_bf16(A1.f, bv[ty][1].f,
                                                            acc[1][1], 0, 0, 0);
      }
    }
    bp += 8192;
    c0 = nx0;
    c1 = nx1;
  }
  // epilogue: C/D 32x32 layout col=lane&31, row=(reg&3)+8*(reg>>2)+4*q
#pragma unroll
  for (int mt = 0; mt < 2; mt++)
#pragma unroll
    for (int nt = 0; nt < 2; nt++) {
      int col = nb * 128 + wn * 64 + nt * 32 + l32;
      int rowb = rb * 128 + wm * 64 + mt * 32 + 4 * q;
#pragma unroll
      for (int r = 0; r < 16; r++) {
        int row = rowb + (r & 3) + 8 * (r >> 2);
        atomicAdd(out + (size_t)row * 256 + col, acc[mt][nt][r]);
      }
    }
}

extern "C" void kernel_launch(void* const* d_in, const int* in_sizes, int n_in,
                              void* d_out, int out_size, void* d_ws,
                              size_t ws_size, hipStream_t stream) {
  const float* V = (const float*)d_in[0];
  const int* adj = (const int*)d_in[1];
  const float* w1 = (const float*)d_in[2];
  const float* w2 = (const float*)d_in[3];
  const float* w3 = (const float*)d_in[4];
  const float* bias = (const float*)d_in[5];
  float* out = (float*)d_out;
  unsigned short* Bp = (unsigned short*)d_ws;               // 12.58 MB
  unsigned* adj2 = (unsigned*)((char*)d_ws + 0xC00000);     // 16 MB @ +12.58 MB
  // workspace requirement: 0xC00000 + 0x1000000 = 29,360,128 bytes

  k_prep<<<dim3(2048), dim3(256), 0, stream>>>(adj, bias, adj2, out);
  k_transform<<<dim3(768), dim3(256), 0, stream>>>(V, w1, w2, w3, Bp);
  k_agg<<<dim3(1024), dim3(256), 0, stream>>>(adj2, Bp, out);
}